// Round 10
// baseline (590.998 us; speedup 1.0000x reference)
//
#include <hip/hip_runtime.h>
#include <math.h>

#define NNODES 65536
#define NEDGES 1048576
#define NF 32
#define EF 16
#define HD 128
#define NACT 10
#define NB 64
#define NPER 1024

typedef unsigned short u16;
typedef float  vf2  __attribute__((ext_vector_type(2)));
typedef float  vf4  __attribute__((ext_vector_type(4)));
typedef __bf16 vbf8 __attribute__((ext_vector_type(8)));
#define BC8(v) __builtin_bit_cast(vbf8, v)
#define WB() __builtin_amdgcn_wave_barrier()   // compile-time phase fence, no HW cost

__device__ __forceinline__ float leakyf(float v) { return v > 0.0f ? v : 0.01f * v; }
__device__ __forceinline__ vf2 fma2(vf2 a, vf2 b, vf2 c) { return __builtin_elementwise_fma(a, b, c); }
__device__ __forceinline__ vf2 max2(vf2 a, vf2 b) { return __builtin_elementwise_max(a, b); }
__device__ __forceinline__ vf2 splat2(float s) { vf2 r = {s, s}; return r; }

__device__ __forceinline__ u16 f2bf(float x) {
    unsigned u = __float_as_uint(x);
    return (u16)((u + 0x7FFFu + ((u >> 16) & 1u)) >> 16);
}
__device__ __forceinline__ float bf2f(u16 h) { return __uint_as_float(((unsigned)h) << 16); }

// split f32x4 into bf16-hi and bf16-lo packed pairs (hi + lo ~= full f32 precision)
__device__ __forceinline__ void cvt4(const float4 s, uint2& hi, uint2& lo) {
    const u16 h0 = f2bf(s.x), h1 = f2bf(s.y), h2 = f2bf(s.z), h3 = f2bf(s.w);
    hi = make_uint2((unsigned)h0 | ((unsigned)h1 << 16), (unsigned)h2 | ((unsigned)h3 << 16));
    const u16 l0 = f2bf(s.x - bf2f(h0)), l1 = f2bf(s.y - bf2f(h1));
    const u16 l2 = f2bf(s.z - bf2f(h2)), l3 = f2bf(s.w - bf2f(h3));
    lo = make_uint2((unsigned)l0 | ((unsigned)l1 << 16), (unsigned)l2 | ((unsigned)l3 << 16));
}
// hi-only variant (internal activations)
__device__ __forceinline__ uint2 cvt4hi(const float4 s) {
    const u16 h0 = f2bf(s.x), h1 = f2bf(s.y), h2 = f2bf(s.z), h3 = f2bf(s.w);
    return make_uint2((unsigned)h0 | ((unsigned)h1 << 16), (unsigned)h2 | ((unsigned)h3 << 16));
}

// ---------------- CSR build: histogram -> scan -> scatter(idx) -> gather-permute ----------------
__global__ __launch_bounds__(256) void hist_kernel(const int* __restrict__ ei, int* __restrict__ cnt)
{
    const int i = blockIdx.x * 256 + threadIdx.x;
    if (i < NEDGES) atomicAdd(&cnt[ei[NEDGES + i]], 1);
}

__global__ __launch_bounds__(1024) void scan_kernel(const int* __restrict__ cnt, int* __restrict__ rs)
{
    __shared__ int s[1024];
    const int t = threadIdx.x;
    int loc[64];
    int tot = 0;
    const int4* c4 = (const int4*)(cnt + t * 64);
    #pragma unroll
    for (int j = 0; j < 16; ++j) {
        const int4 v = c4[j];
        loc[4*j+0] = v.x; loc[4*j+1] = v.y; loc[4*j+2] = v.z; loc[4*j+3] = v.w;
        tot += v.x + v.y + v.z + v.w;
    }
    s[t] = tot;
    __syncthreads();
    for (int off = 1; off < 1024; off <<= 1) {
        const int v = (t >= off) ? s[t - off] : 0;
        __syncthreads();
        s[t] += v;
        __syncthreads();
    }
    int run = s[t] - tot;
    #pragma unroll
    for (int j = 0; j < 64; ++j) { rs[t * 64 + j] = run; run += loc[j]; }
    if (t == 0) rs[NNODES] = NEDGES;
}

__global__ __launch_bounds__(256) void scatter_kernel(
    const int* __restrict__ ei, const int* __restrict__ rs, int* __restrict__ fill,
    int* __restrict__ ssrc, int* __restrict__ seidx)
{
    const int i = blockIdx.x * 256 + threadIdx.x;
    if (i < NEDGES) {
        const int d = ei[NEDGES + i];
        const int pos = rs[d] + atomicAdd(&fill[d], 1);
        ssrc[pos]  = ei[i];
        seidx[pos] = i;
    }
}

__global__ __launch_bounds__(256) void permute_kernel(
    const int* __restrict__ seidx, const float* __restrict__ ea, float* __restrict__ sea)
{
    const int t = blockIdx.x * 256 + threadIdx.x;
    const int e = t >> 2, part = t & 3;
    const int idx = seidx[e];
    ((float4*)sea)[(size_t)e * 4 + part] = ((const float4*)ea)[(size_t)idx * 4 + part];
}

// ---------------- weight packing (all 6 matrices, one launch) ----------------
__global__ __launch_bounds__(256) void pack_all_kernel(
    const float* __restrict__ w0, const float* __restrict__ w1, const float* __restrict__ w2,
    const float* __restrict__ w3, const float* __restrict__ w4, const float* __restrict__ w5,
    u16* __restrict__ pw)
{
    const int bid = blockIdx.x;
    const float* W; int KB, seg, sbase;
    if (bid < 16) { W = w0; KB = 1; seg = 0; sbase = 0; }
    else {
        const int i = (bid - 16) >> 6;
        seg = i + 1; sbase = 16 + i * 64; KB = 4;
        W = (i == 0) ? w1 : (i == 1) ? w2 : (i == 2) ? w3 : (i == 3) ? w4 : w5;
    }
    const int t = (bid - sbase) * 256 + threadIdx.x;
    const int j = t & 7, lane = (t >> 3) & 63, rest = t >> 9;
    const int kb = rest % KB, fb = rest / KB;
    if (fb >= 8) return;
    const int k = kb * 32 + (lane >> 4) * 8 + j;
    const int f = fb * 16 + (lane & 15);
    const float val = W[k * HD + f];
    const u16 h = f2bf(val);
    u16* dst = pw + seg * 32768;
    dst[t] = h;
    dst[16384 + t] = f2bf(val - bf2f(h));
}

// ---------------- edge layer 1 (gather): row-preloaded src, 4 chains x 2-deep unroll ----------------
// One wave per node. lane = (chain q, feature pair p): chain q handles edges j = q, q+4, q+8, ...
// src indices preloaded into sv (one coalesced load per node row), fetched via shfl -> no
// per-iteration ssrc load in the dependency chain; 8 x-gathers in flight per wave.
__global__ __launch_bounds__(256) void e1_agg_kernel(
    const float* __restrict__ x, const int* __restrict__ rs,
    const int* __restrict__ ssrc, const float* __restrict__ sea,
    const float* __restrict__ w, const float* __restrict__ b, float* __restrict__ agg)
{
    const int tid  = threadIdx.x;
    const int lane = tid & 63;
    const int p    = lane & 15;          // feature pair: f = 2p, 2p+1
    const int q    = lane >> 4;          // edge chain 0..3
    const int node = blockIdx.x * 4 + (tid >> 6);
    vf2 wr[EF];
    #pragma unroll
    for (int k = 0; k < EF; ++k) wr[k] = *(const vf2*)&w[k * NF + p * 2];
    const vf2 bias = *(const vf2*)&b[p * 2];
    const int beg = rs[node], end = rs[node + 1];
    const int deg = end - beg;
    const int n64 = deg < 64 ? deg : 64;
    int sv = 0;
    if (lane < n64) sv = ssrc[beg + lane];
    vf2 acc = {0.0f, 0.0f};
    int j = q;
    for (; j + 4 < n64; j += 8) {        // edges j and j+4 of this chain
        const int sA = __shfl(sv, j, 64);
        const int sB = __shfl(sv, j + 4, 64);
        const vf2 xA = *(const vf2*)((const char*)x + (((unsigned)sA << 7) + (unsigned)p * 8));
        const vf2 xB = *(const vf2*)((const char*)x + (((unsigned)sB << 7) + (unsigned)p * 8));
        const float4* pA = (const float4*)sea + (size_t)(beg + j) * 4;
        const float4* pB = (const float4*)sea + (size_t)(beg + j + 4) * 4;
        const float4 A0 = pA[0], A1 = pA[1], A2 = pA[2], A3 = pA[3];
        const float4 B0 = pB[0], B1 = pB[1], B2 = pB[2], B3 = pB[3];
        vf2 mA = bias, mB = bias;
        mA = fma2(splat2(A0.x), wr[0],  mA); mB = fma2(splat2(B0.x), wr[0],  mB);
        mA = fma2(splat2(A0.y), wr[1],  mA); mB = fma2(splat2(B0.y), wr[1],  mB);
        mA = fma2(splat2(A0.z), wr[2],  mA); mB = fma2(splat2(B0.z), wr[2],  mB);
        mA = fma2(splat2(A0.w), wr[3],  mA); mB = fma2(splat2(B0.w), wr[3],  mB);
        mA = fma2(splat2(A1.x), wr[4],  mA); mB = fma2(splat2(B1.x), wr[4],  mB);
        mA = fma2(splat2(A1.y), wr[5],  mA); mB = fma2(splat2(B1.y), wr[5],  mB);
        mA = fma2(splat2(A1.z), wr[6],  mA); mB = fma2(splat2(B1.z), wr[6],  mB);
        mA = fma2(splat2(A1.w), wr[7],  mA); mB = fma2(splat2(B1.w), wr[7],  mB);
        mA = fma2(splat2(A2.x), wr[8],  mA); mB = fma2(splat2(B2.x), wr[8],  mB);
        mA = fma2(splat2(A2.y), wr[9],  mA); mB = fma2(splat2(B2.y), wr[9],  mB);
        mA = fma2(splat2(A2.z), wr[10], mA); mB = fma2(splat2(B2.z), wr[10], mB);
        mA = fma2(splat2(A2.w), wr[11], mA); mB = fma2(splat2(B2.w), wr[11], mB);
        mA = fma2(splat2(A3.x), wr[12], mA); mB = fma2(splat2(B3.x), wr[12], mB);
        mA = fma2(splat2(A3.y), wr[13], mA); mB = fma2(splat2(B3.y), wr[13], mB);
        mA = fma2(splat2(A3.z), wr[14], mA); mB = fma2(splat2(B3.z), wr[14], mB);
        mA = fma2(splat2(A3.w), wr[15], mA); mB = fma2(splat2(B3.w), wr[15], mB);
        acc += max2(xA + mA, splat2(0.0f));       // same per-chain order as before:
        acc += max2(xB + mB, splat2(0.0f));       // edge j, then edge j+4
    }
    if (j < n64) {
        const int sA = __shfl(sv, j, 64);
        const vf2 xA = *(const vf2*)((const char*)x + (((unsigned)sA << 7) + (unsigned)p * 8));
        const float4* pA = (const float4*)sea + (size_t)(beg + j) * 4;
        const float4 A0 = pA[0], A1 = pA[1], A2 = pA[2], A3 = pA[3];
        vf2 m = bias;
        m = fma2(splat2(A0.x), wr[0],  m); m = fma2(splat2(A0.y), wr[1],  m);
        m = fma2(splat2(A0.z), wr[2],  m); m = fma2(splat2(A0.w), wr[3],  m);
        m = fma2(splat2(A1.x), wr[4],  m); m = fma2(splat2(A1.y), wr[5],  m);
        m = fma2(splat2(A1.z), wr[6],  m); m = fma2(splat2(A1.w), wr[7],  m);
        m = fma2(splat2(A2.x), wr[8],  m); m = fma2(splat2(A2.y), wr[9],  m);
        m = fma2(splat2(A2.z), wr[10], m); m = fma2(splat2(A2.w), wr[11], m);
        m = fma2(splat2(A3.x), wr[12], m); m = fma2(splat2(A3.y), wr[13], m);
        m = fma2(splat2(A3.z), wr[14], m); m = fma2(splat2(A3.w), wr[15], m);
        acc += max2(xA + m, splat2(0.0f));
    }
    for (int e = beg + 64 + q; e < end; e += 4) {   // rare: degree > 64 (chain order continues)
        const int sA = ssrc[e];
        const vf2 xA = *(const vf2*)((const char*)x + (((unsigned)sA << 7) + (unsigned)p * 8));
        const float4* pA = (const float4*)sea + (size_t)e * 4;
        const float4 A0 = pA[0], A1 = pA[1], A2 = pA[2], A3 = pA[3];
        vf2 m = bias;
        m = fma2(splat2(A0.x), wr[0],  m); m = fma2(splat2(A0.y), wr[1],  m);
        m = fma2(splat2(A0.z), wr[2],  m); m = fma2(splat2(A0.w), wr[3],  m);
        m = fma2(splat2(A1.x), wr[4],  m); m = fma2(splat2(A1.y), wr[5],  m);
        m = fma2(splat2(A1.z), wr[6],  m); m = fma2(splat2(A1.w), wr[7],  m);
        m = fma2(splat2(A2.x), wr[8],  m); m = fma2(splat2(A2.y), wr[9],  m);
        m = fma2(splat2(A2.z), wr[10], m); m = fma2(splat2(A2.w), wr[11], m);
        m = fma2(splat2(A3.x), wr[12], m); m = fma2(splat2(A3.y), wr[13], m);
        m = fma2(splat2(A3.z), wr[14], m); m = fma2(splat2(A3.w), wr[15], m);
        acc += max2(xA + m, splat2(0.0f));
    }
    acc[0] += __shfl_xor(acc[0], 16, 64); acc[1] += __shfl_xor(acc[1], 16, 64);
    acc[0] += __shfl_xor(acc[0], 32, 64); acc[1] += __shfl_xor(acc[1], 32, 64);
    if (lane < 16) *(vf2*)&agg[(size_t)node * NF + p * 2] = acc;
}

// ---------------- edge layer 2 (gather): scalar-uniform sea/ssrc + pk_fma ----------------
__global__ __launch_bounds__(256) void e2_agg_kernel(
    const float* __restrict__ h, const int* __restrict__ rs,
    const int* __restrict__ ssrc, const float* __restrict__ sea,
    const float* __restrict__ w, const float* __restrict__ b, float* __restrict__ agg)
{
    const int tid  = threadIdx.x;
    const int lane = tid & 63;
    const unsigned foff = (unsigned)lane * 8;    // byte offset of feature pair
    const int node = blockIdx.x * 4 + (tid >> 6);
    vf2 wr[EF];
    #pragma unroll
    for (int k = 0; k < EF; ++k) wr[k] = *(const vf2*)&w[k * HD + lane * 2];
    const vf2 bias = *(const vf2*)&b[lane * 2];
    const int beg = __builtin_amdgcn_readfirstlane(rs[node]);
    const int end = __builtin_amdgcn_readfirstlane(rs[node + 1]);
    vf2 acc = {0.0f, 0.0f};
    int e = beg;
    for (; e + 2 <= end; e += 2) {
        const int sA = ssrc[e];                  // uniform -> s_load
        const int sB = ssrc[e + 1];
        const vf2 hA = *(const vf2*)((const char*)h + (((unsigned)sA << 9) + foff));
        const vf2 hB = *(const vf2*)((const char*)h + (((unsigned)sB << 9) + foff));
        const float* aA = &sea[(size_t)e * EF];  // uniform -> s_load_dwordx16
        const float* aB = aA + EF;
        vf2 mA = bias, mB = bias;
        #pragma unroll
        for (int k = 0; k < EF; ++k) {
            mA = fma2(splat2(aA[k]), wr[k], mA);
            mB = fma2(splat2(aB[k]), wr[k], mB);
        }
        acc += max2(hA + mA, splat2(0.0f));
        acc += max2(hB + mB, splat2(0.0f));
    }
    if (e < end) {
        const int sA = ssrc[e];
        const vf2 hA = *(const vf2*)((const char*)h + (((unsigned)sA << 9) + foff));
        const float* aA = &sea[(size_t)e * EF];
        vf2 mA = bias;
        #pragma unroll
        for (int k = 0; k < EF; ++k) mA = fma2(splat2(aA[k]), wr[k], mA);
        acc += max2(hA + mA, splat2(0.0f));
    }
    *(vf2*)&agg[(size_t)node * HD + lane * 2] = acc;
}

// ---------------- MFMA node-GEMM building blocks ----------------
#define ROW128 272   // 128 bf16 = 256 B + 16 pad
#define ROW32  80    // 32 bf16 = 64 B + 16 pad

// layer consuming STAGED input (hi+lo B): 3 MFMAs per (fb,kb)
__device__ __forceinline__ void mfma_layer128_in(
    const unsigned char* __restrict__ aH, const unsigned char* __restrict__ aL,
    const u16* __restrict__ wH, const u16* __restrict__ wL,
    const float* __restrict__ bias, int lane, vf4* __restrict__ acc)
{
    const int quad = lane >> 4, fm = lane & 15;
    int4 Bh[4], Bl[4];
    #pragma unroll
    for (int kb = 0; kb < 4; ++kb) {
        Bh[kb] = *(const int4*)(aH + fm * ROW128 + kb * 64 + quad * 16);
        Bl[kb] = *(const int4*)(aL + fm * ROW128 + kb * 64 + quad * 16);
    }
    #pragma unroll
    for (int fb = 0; fb < 8; ++fb) {
        const float4 bv = *(const float4*)&bias[fb * 16 + quad * 4];
        vf4 a = {bv.x, bv.y, bv.z, bv.w};
        #pragma unroll
        for (int kb = 0; kb < 4; ++kb) {
            const int4 wh = *(const int4*)(wH + ((fb * 4 + kb) * 64 + lane) * 8);
            const int4 wl = *(const int4*)(wL + ((fb * 4 + kb) * 64 + lane) * 8);
            a = __builtin_amdgcn_mfma_f32_16x16x32_bf16(BC8(wh), BC8(Bl[kb]), a, 0, 0, 0);
            a = __builtin_amdgcn_mfma_f32_16x16x32_bf16(BC8(wl), BC8(Bh[kb]), a, 0, 0, 0);
            a = __builtin_amdgcn_mfma_f32_16x16x32_bf16(BC8(wh), BC8(Bh[kb]), a, 0, 0, 0);
        }
        acc[fb] = a;
    }
}

// layer consuming internal ACTIVATIONS (hi-only B): 2 MFMAs per (fb,kb)
__device__ __forceinline__ void mfma_layer128_act(
    const unsigned char* __restrict__ aH,
    const u16* __restrict__ wH, const u16* __restrict__ wL,
    const float* __restrict__ bias, int lane, vf4* __restrict__ acc)
{
    const int quad = lane >> 4, fm = lane & 15;
    int4 Bh[4];
    #pragma unroll
    for (int kb = 0; kb < 4; ++kb)
        Bh[kb] = *(const int4*)(aH + fm * ROW128 + kb * 64 + quad * 16);
    #pragma unroll
    for (int fb = 0; fb < 8; ++fb) {
        const float4 bv = *(const float4*)&bias[fb * 16 + quad * 4];
        vf4 a = {bv.x, bv.y, bv.z, bv.w};
        #pragma unroll
        for (int kb = 0; kb < 4; ++kb) {
            const int4 wh = *(const int4*)(wH + ((fb * 4 + kb) * 64 + lane) * 8);
            const int4 wl = *(const int4*)(wL + ((fb * 4 + kb) * 64 + lane) * 8);
            a = __builtin_amdgcn_mfma_f32_16x16x32_bf16(BC8(wl), BC8(Bh[kb]), a, 0, 0, 0);
            a = __builtin_amdgcn_mfma_f32_16x16x32_bf16(BC8(wh), BC8(Bh[kb]), a, 0, 0, 0);
        }
        acc[fb] = a;
    }
}

__device__ __forceinline__ void mfma_layer32_in(
    const unsigned char* __restrict__ aH, const unsigned char* __restrict__ aL,
    const u16* __restrict__ wH, const u16* __restrict__ wL,
    const float* __restrict__ bias, int lane, vf4* __restrict__ acc)
{
    const int quad = lane >> 4, fm = lane & 15;
    const int4 Bh = *(const int4*)(aH + fm * ROW32 + quad * 16);
    const int4 Bl = *(const int4*)(aL + fm * ROW32 + quad * 16);
    #pragma unroll
    for (int fb = 0; fb < 8; ++fb) {
        const float4 bv = *(const float4*)&bias[fb * 16 + quad * 4];
        vf4 a = {bv.x, bv.y, bv.z, bv.w};
        const int4 wh = *(const int4*)(wH + (fb * 64 + lane) * 8);
        const int4 wl = *(const int4*)(wL + (fb * 64 + lane) * 8);
        a = __builtin_amdgcn_mfma_f32_16x16x32_bf16(BC8(wh), BC8(Bl), a, 0, 0, 0);
        a = __builtin_amdgcn_mfma_f32_16x16x32_bf16(BC8(wl), BC8(Bh), a, 0, 0, 0);
        a = __builtin_amdgcn_mfma_f32_16x16x32_bf16(BC8(wh), BC8(Bh), a, 0, 0, 0);
        acc[fb] = a;
    }
}

// apply leaky, write hi-only activations to LDS (acc updated to post-activation values)
__device__ __forceinline__ void store_act_hi(
    unsigned char* __restrict__ aH, int lane, vf4* __restrict__ acc)
{
    const int quad = lane >> 4, fm = lane & 15;
    #pragma unroll
    for (int fb = 0; fb < 8; ++fb) {
        const float4 s = {leakyf(acc[fb][0]), leakyf(acc[fb][1]), leakyf(acc[fb][2]), leakyf(acc[fb][3])};
        acc[fb][0] = s.x; acc[fb][1] = s.y; acc[fb][2] = s.z; acc[fb][3] = s.w;
        *(uint2*)(aH + fm * ROW128 + fb * 32 + quad * 8) = cvt4hi(s);
    }
}

// ---------------- node MLP layer 1 (MFMA, wave-private slab, NO block barriers) ----------------
__global__ __launch_bounds__(256) void n1_kernel(
    const float* __restrict__ x, const float* __restrict__ agg,
    const u16* __restrict__ w1h, const u16* __restrict__ w1l, const float* __restrict__ b1,
    const u16* __restrict__ w2h, const u16* __restrict__ w2l, const float* __restrict__ b2,
    float* __restrict__ hout)
{
    __shared__ __align__(16) unsigned char smem[4][2560 + 16 * ROW128];
    const int tid = threadIdx.x, lane = tid & 63, wid = tid >> 6;
    const int quad = lane >> 4, fm = lane & 15;
    const int tile = blockIdx.x * 4 + wid;
    unsigned char* inH = smem[wid];
    unsigned char* inL = inH + 16 * ROW32;
    unsigned char* aH  = inH + 2560;
    const size_t base = (size_t)tile * 16 * NF;
    #pragma unroll
    for (int i = 0; i < 2; ++i) {
        const int flat = i * 64 + lane;
        const int node = flat >> 3, kq = flat & 7;
        const float4 xv = *(const float4*)&x[base + node * NF + kq * 4];
        const float4 av = *(const float4*)&agg[base + node * NF + kq * 4];
        const float4 s = {xv.x + av.x, xv.y + av.y, xv.z + av.z, xv.w + av.w};
        uint2 phi, plo;
        cvt4(s, phi, plo);
        *(uint2*)(inH + node * ROW32 + kq * 8) = phi;
        *(uint2*)(inL + node * ROW32 + kq * 8) = plo;
    }
    WB();
    vf4 acc[8];
    mfma_layer32_in(inH, inL, w1h, w1l, b1, lane, acc);
    WB();
    store_act_hi(aH, lane, acc);
    WB();
    mfma_layer128_act(aH, w2h, w2l, b2, lane, acc);
    const size_t ob = (size_t)tile * 16 * HD;
    #pragma unroll
    for (int fb = 0; fb < 8; ++fb) {
        const float4 o = {fmaxf(acc[fb][0], 0.0f), fmaxf(acc[fb][1], 0.0f),
                          fmaxf(acc[fb][2], 0.0f), fmaxf(acc[fb][3], 0.0f)};
        *(float4*)&hout[ob + fm * HD + fb * 16 + quad * 4] = o;
    }
}

// ---- node layer 2 + pooling + node-score head (MFMA, wave-private slab, NO block barriers) ----
__global__ __launch_bounds__(256) void n2_kernel(
    const float* __restrict__ h, const float* __restrict__ agg,
    const u16* __restrict__ w1h, const u16* __restrict__ w1l, const float* __restrict__ b1,
    const u16* __restrict__ w2h, const u16* __restrict__ w2l, const float* __restrict__ b2,
    const u16* __restrict__ m1h, const u16* __restrict__ m1l, const float* __restrict__ nb1,
    const u16* __restrict__ m2h, const u16* __restrict__ m2l, const float* __restrict__ nb2,
    const float* __restrict__ nw3, const float* __restrict__ nb3,
    float* __restrict__ pooled, float* __restrict__ scores)
{
    __shared__ __align__(16) unsigned char smem[4][2 * 16 * ROW128];
    const int tid = threadIdx.x, lane = tid & 63, wid = tid >> 6;
    const int quad = lane >> 4, fm = lane & 15;
    const int tile = blockIdx.x * 4 + wid;
    unsigned char* aH = smem[wid];
    unsigned char* aL = aH + 16 * ROW128;
    const size_t base = (size_t)tile * 16 * HD;
    #pragma unroll
    for (int i = 0; i < 8; ++i) {
        const int flat = i * 64 + lane;
        const int node = flat >> 5, kq = flat & 31;
        const float4 hv = *(const float4*)&h[base + node * HD + kq * 4];
        const float4 av = *(const float4*)&agg[base + node * HD + kq * 4];
        const float4 s = {hv.x + av.x, hv.y + av.y, hv.z + av.z, hv.w + av.w};
        uint2 phi, plo;
        cvt4(s, phi, plo);
        *(uint2*)(aH + node * ROW128 + kq * 8) = phi;
        *(uint2*)(aL + node * ROW128 + kq * 8) = plo;
    }
    WB();
    vf4 acc[8];
    mfma_layer128_in(aH, aL, w1h, w1l, b1, lane, acc);   // consumes staged hi+lo
    WB();
    store_act_hi(aH, lane, acc);                          // aL dead from here on
    WB();
    mfma_layer128_act(aH, w2h, w2l, b2, lane, acc);
    WB();
    store_act_hi(aH, lane, acc);                          // acc now holds h2 (leaky'd)
    {
        const int g = tile >> 6;
        #pragma unroll
        for (int fb = 0; fb < 8; ++fb) {
            vf4 t = acc[fb];
            #pragma unroll
            for (int off = 1; off < 16; off <<= 1) {
                t[0] += __shfl_xor(t[0], off, 64);
                t[1] += __shfl_xor(t[1], off, 64);
                t[2] += __shfl_xor(t[2], off, 64);
                t[3] += __shfl_xor(t[3], off, 64);
            }
            #pragma unroll
            for (int r = 0; r < 4; ++r) {
                const int item = fb * 4 + r;
                if (fm == (item >> 1))
                    atomicAdd(&pooled[g * HD + fb * 16 + quad * 4 + r], t[r]);
            }
        }
    }
    WB();
    mfma_layer128_act(aH, m1h, m1l, nb1, lane, acc);
    WB();
    store_act_hi(aH, lane, acc);
    WB();
    mfma_layer128_act(aH, m2h, m2l, nb2, lane, acc);
    float v = 0.0f;
    #pragma unroll
    for (int fb = 0; fb < 8; ++fb) {
        const float4 w3v = *(const float4*)&nw3[fb * 16 + quad * 4];
        v += leakyf(acc[fb][0]) * w3v.x + leakyf(acc[fb][1]) * w3v.y
           + leakyf(acc[fb][2]) * w3v.z + leakyf(acc[fb][3]) * w3v.w;
    }
    v += __shfl_xor(v, 16, 64);
    v += __shfl_xor(v, 32, 64);
    if (lane < 16) {
        const int node = tile * 16 + fm;
        const float s = v + nb3[0];
        scores[(node & 63) * NPER + (node >> 6)] = 1.0f / (1.0f + expf(-s));
    }
}

// ---------------- action head: pooled mean -> MLP -> softmax ----------------
__global__ __launch_bounds__(128) void act_kernel(
    const float* __restrict__ pooled,
    const float* __restrict__ w1, const float* __restrict__ b1,
    const float* __restrict__ w2, const float* __restrict__ b2,
    float* __restrict__ out)
{
    __shared__ __align__(16) float p[HD];
    __shared__ float a1[HD];
    __shared__ float z[NACT];
    __shared__ float red2[2];
    const int g = blockIdx.x;
    const int tid = threadIdx.x;
    p[tid] = pooled[g * HD + tid] * (1.0f / NPER);
    __syncthreads();
    float acc = b1[tid];
    for (int k = 0; k < HD; ++k) acc = fmaf(p[k], w1[k * HD + tid], acc);
    a1[tid] = leakyf(acc);
    __syncthreads();
    if (tid < NACT) {
        float a2 = b2[tid];
        for (int k = 0; k < HD; ++k) a2 = fmaf(a1[k], w2[k * NACT + tid], a2);
        z[tid] = leakyf(a2);
    }
    __syncthreads();
    if (tid == 0) {
        float m = z[0];
        for (int i = 1; i < NACT; ++i) m = fmaxf(m, z[i]);
        red2[0] = m;
    }
    __syncthreads();
    if (tid < NACT) z[tid] = expf(z[tid] - red2[0]);
    __syncthreads();
    if (tid == 0) {
        float s = 0.0f;
        for (int i = 0; i < NACT; ++i) s += z[i];
        red2[1] = s;
    }
    __syncthreads();
    if (tid < NACT) out[g * NACT + tid] = z[tid] / red2[1];
}

extern "C" void kernel_launch(void* const* d_in, const int* in_sizes, int n_in,
                              void* d_out, int out_size, void* d_ws, size_t ws_size,
                              hipStream_t stream)
{
    const float* x    = (const float*)d_in[0];
    const int*   ei   = (const int*)d_in[1];     // int32
    const float* ea   = (const float*)d_in[2];
    const float* e1w  = (const float*)d_in[3];
    const float* e1b  = (const float*)d_in[4];
    const float* c1w1 = (const float*)d_in[5];
    const float* c1b1 = (const float*)d_in[6];
    const float* c1w2 = (const float*)d_in[7];
    const float* c1b2 = (const float*)d_in[8];
    const float* e2w  = (const float*)d_in[9];
    const float* e2b  = (const float*)d_in[10];
    const float* c2w1 = (const float*)d_in[11];
    const float* c2b1 = (const float*)d_in[12];
    const float* c2w2 = (const float*)d_in[13];
    const float* c2b2 = (const float*)d_in[14];
    const float* aw1  = (const float*)d_in[15];
    const float* ab1  = (const float*)d_in[16];
    const float* aw2  = (const float*)d_in[17];
    const float* ab2  = (const float*)d_in[18];
    const float* nw1  = (const float*)d_in[19];
    const float* nb1  = (const float*)d_in[20];
    const float* nw2  = (const float*)d_in[21];
    const float* nb2  = (const float*)d_in[22];
    const float* nw3  = (const float*)d_in[23];
    const float* nb3  = (const float*)d_in[24];

    float* out = (float*)d_out;
    char*  ws  = (char*)d_ws;
    const size_t MB = 1024 * 1024;
    float* h      = (float*)(ws);
    float* agg2   = (float*)(ws + 32  * MB);
    int*   seidx  = (int*)  (ws + 32  * MB);     // dead before e2_agg writes agg2
    float* sea    = (float*)(ws + 64  * MB);
    float* agg1   = (float*)(ws + 128 * MB);
    float* pooled = (float*)(ws + 136 * MB);
    u16*   pw     = (u16*)  (ws + 136 * MB + 64 * 1024);
    int*   cnt    = (int*)  (ws + 137 * MB);
    int*   fill   = (int*)  (ws + 137 * MB + 256 * 1024);
    int*   rs     = (int*)  (ws + 139 * MB);
    int*   ssrc   = (int*)  (ws + 140 * MB);

    u16* p_c1w1 = pw;
    u16* p_c1w2 = pw + 1 * 32768;
    u16* p_c2w1 = pw + 2 * 32768;
    u16* p_c2w2 = pw + 3 * 32768;
    u16* p_nw1  = pw + 4 * 32768;
    u16* p_nw2  = pw + 5 * 32768;

    hipMemsetAsync(cnt,    0, 2 * NNODES * sizeof(int), stream);
    hipMemsetAsync(pooled, 0, (size_t)NB * HD * sizeof(float), stream);

    pack_all_kernel<<<336, 256, 0, stream>>>(c1w1, c1w2, c2w1, c2w2, nw1, nw2, pw);

    hist_kernel<<<NEDGES / 256, 256, 0, stream>>>(ei, cnt);
    scan_kernel<<<1, 1024, 0, stream>>>(cnt, rs);
    scatter_kernel<<<NEDGES / 256, 256, 0, stream>>>(ei, rs, fill, ssrc, seidx);
    permute_kernel<<<NEDGES / 64, 256, 0, stream>>>(seidx, ea, sea);

    e1_agg_kernel<<<NNODES / 4, 256, 0, stream>>>(x, rs, ssrc, sea, e1w, e1b, agg1);
    n1_kernel<<<NNODES / 64, 256, 0, stream>>>(x, agg1,
                                               p_c1w1, p_c1w1 + 16384, c1b1,
                                               p_c1w2, p_c1w2 + 16384, c1b2, h);
    e2_agg_kernel<<<NNODES / 4, 256, 0, stream>>>(h, rs, ssrc, sea, e2w, e2b, agg2);
    n2_kernel<<<NNODES / 64, 256, 0, stream>>>(h, agg2,
                                               p_c2w1, p_c2w1 + 16384, c2b1,
                                               p_c2w2, p_c2w2 + 16384, c2b2,
                                               p_nw1,  p_nw1  + 16384, nb1,
                                               p_nw2,  p_nw2  + 16384, nb2,
                                               nw3, nb3, pooled, out + NB * NACT);
    act_kernel<<<NB, 128, 0, stream>>>(pooled, aw1, ab1, aw2, ab2, out);
}